// Round 8
// baseline (403.732 us; speedup 1.0000x reference)
//
#include <hip/hip_runtime.h>
#include <hip/hip_fp16.h>
#include <math.h>
#include <stdint.h>

// ---------------- problem constants ----------------
#define CUTOFF_F     5.0f
#define INV_CUTOFF   0.2f
#define KCOUL        14.3996454784936f
#define INV_SQRT2    0.7071067811865475f

// clang native vectors (HIP_vector_type is rejected by nontemporal builtins)
typedef int            vint4    __attribute__((ext_vector_type(4)));
typedef float          vfloat4  __attribute__((ext_vector_type(4)));
typedef uint32_t       vuint4   __attribute__((ext_vector_type(4)));

// ---------------- plan ----------------
// ROUND-8: FUSE THE PHYSICS INTO p1.
// p2 sat at ~142us across FOUR structures; its per-edge serial chain
// (random sigma gather + ~25-op edge_val + cum walk) is the invariant.
// p1 has VALUBusy 5.6% and holds src/dst/bond in registers anyway.
// So: p1 gathers sigma[src]/sigma[dst] (2MB table, L2-resident; 16
// INDEPENDENT loads batched per unrolled pack loop - MLP, unlike round-2's
// serial per-iteration gather), computes v = edge_val(...), and emits ONE
// u32 record per edge: (local_dst << 16) | fp16(v).
// p2 per edge: load u32 -> ds_add. No sigma, no erf, no fp16-r decode.
// Output traffic 98->64MB each way; p2 LDS ~11.5KB (sig window deleted).
// p3 unchanged.
#define WSHIFT        11
#define WINDOW        2048
#define NB            245                       // ceil(500000/2048)
#define EPT           8
#define EPB           4096                      // 2 batches * 256 thr * 8
#define OFFS_STRIDE   256                       // u16 slots per block (246 used)
#define SPAN_MAX      512                       // max p1-blocks per p2 wg

// A&S 7.1.26 erf approx, x>=0, max abs err 1.5e-7
__device__ __forceinline__ float erf_approx(float x) {
    const float a1 = 0.254829592f, a2 = -0.284496736f, a3 = 1.421413741f,
                a4 = -1.453152027f, a5 = 1.061405429f, p = 0.3275911f;
    float t = __builtin_amdgcn_rcpf(fmaf(p, x, 1.0f));
    float poly = t * fmaf(t, fmaf(t, fmaf(t, fmaf(t, a5, a4), a3), a2), a1);
    return 1.0f - poly * __expf(-x * x);
}

// per-edge value WITHOUT the charge[dst] factor; s2sum = sig_s^2 + sig_d^2
__device__ __forceinline__ float edge_val(float rr, float s2sum) {
    float inv_gamma = rsqrtf(s2sum);
    float x  = rr * INV_CUTOFF;
    float fc = fmaf(x * x * x, fmaf(x, fmaf(-6.0f, x, 15.0f), -10.0f), 1.0f);
    fc = (rr <= CUTOFF_F) ? fc : 0.0f;
    return erf_approx(rr * INV_SQRT2 * inv_gamma) * fc * KCOUL
         * __builtin_amdgcn_rcpf(rr);
}

// pack one edge: bucket-rank via LDS hist, record = local<<16 | fp16(v)
__device__ __forceinline__ void pack_edge(
    int dv, int sv_unused, float rv, float ss, float sd,
    uint32_t* hist, uint32_t& br, uint32_t& rec)
{
    unsigned b = (unsigned)dv >> WSHIFT;
    uint32_t rk = atomicAdd(&hist[b], 1u);
    br = (b << 16) | rk;
    float v = edge_val(rv, fmaf(ss, ss, sd * sd));
    rec = ((uint32_t)((unsigned)dv & (WINDOW - 1)) << 16)
        | (uint32_t)__half_as_ushort(__float2half_rn(v));
}

// ---------------- pass 1: counting-sort + fused physics ----------------
__global__ __launch_bounds__(256, 4) void p1_bin(
    const float* __restrict__ bond,
    const int*   __restrict__ src,
    const int*   __restrict__ dst,
    const float* __restrict__ sigma,
    unsigned short* __restrict__ offs,     // [nblk][OFFS_STRIDE] u16 scan table
    uint32_t*       __restrict__ rec_out,  // [nblk][EPB] local<<16 | fp16(v)
    int n_edges)
{
    __shared__ uint32_t hist[NB];
    __shared__ uint32_t scan_s[NB + 1];
    __shared__ alignas(16) uint32_t buf[EPB];   // 16 KB

    const int tid = threadIdx.x;
    const int e0  = blockIdx.x * EPB;

    if (tid < NB) hist[tid] = 0;
    __syncthreads();

    uint32_t recA[EPT], brA[EPT], recB[EPT], brB[EPT];

    const bool full = (e0 + EPB <= n_edges);
    if (full) {
        // ---- batch A: 6 vec4 loads -> 16 independent sigma gathers ->
        //      8 edge_vals -> pack; vector regs die before batch B ----
        {
            const vint4*   dp = (const vint4*)(dst + e0) + tid;
            const vint4*   sp = (const vint4*)(src + e0) + tid;
            const vfloat4* rp = (const vfloat4*)(bond + e0) + tid;
            vint4   d0 = __builtin_nontemporal_load(dp);
            vint4   d1 = __builtin_nontemporal_load(dp + 256);
            vint4   s0 = __builtin_nontemporal_load(sp);
            vint4   s1 = __builtin_nontemporal_load(sp + 256);
            vfloat4 r0 = __builtin_nontemporal_load(rp);
            vfloat4 r1 = __builtin_nontemporal_load(rp + 256);
            int   d[EPT] = {d0.x,d0.y,d0.z,d0.w,d1.x,d1.y,d1.z,d1.w};
            int   s[EPT] = {s0.x,s0.y,s0.z,s0.w,s1.x,s1.y,s1.z,s1.w};
            float r[EPT] = {r0.x,r0.y,r0.z,r0.w,r1.x,r1.y,r1.z,r1.w};
            float ss[EPT], sd[EPT];
            #pragma unroll
            for (int j = 0; j < EPT; ++j) { ss[j] = sigma[s[j]]; sd[j] = sigma[d[j]]; }
            #pragma unroll
            for (int j = 0; j < EPT; ++j)
                pack_edge(d[j], s[j], r[j], ss[j], sd[j], hist, brA[j], recA[j]);
        }
        // ---- batch B: same, offsets +512/+768 ----
        {
            const vint4*   dp = (const vint4*)(dst + e0) + tid;
            const vint4*   sp = (const vint4*)(src + e0) + tid;
            const vfloat4* rp = (const vfloat4*)(bond + e0) + tid;
            vint4   d2 = __builtin_nontemporal_load(dp + 512);
            vint4   d3 = __builtin_nontemporal_load(dp + 768);
            vint4   s2 = __builtin_nontemporal_load(sp + 512);
            vint4   s3 = __builtin_nontemporal_load(sp + 768);
            vfloat4 r2 = __builtin_nontemporal_load(rp + 512);
            vfloat4 r3 = __builtin_nontemporal_load(rp + 768);
            int   d[EPT] = {d2.x,d2.y,d2.z,d2.w,d3.x,d3.y,d3.z,d3.w};
            int   s[EPT] = {s2.x,s2.y,s2.z,s2.w,s3.x,s3.y,s3.z,s3.w};
            float r[EPT] = {r2.x,r2.y,r2.z,r2.w,r3.x,r3.y,r3.z,r3.w};
            float ss[EPT], sd[EPT];
            #pragma unroll
            for (int j = 0; j < EPT; ++j) { ss[j] = sigma[s[j]]; sd[j] = sigma[d[j]]; }
            #pragma unroll
            for (int j = 0; j < EPT; ++j)
                pack_edge(d[j], s[j], r[j], ss[j], sd[j], hist, brB[j], recB[j]);
        }
    } else {
        #pragma unroll
        for (int j = 0; j < EPT; ++j) {
            int eA = e0 + (j >> 2) * 1024 + tid * 4 + (j & 3);
            int eB = eA + 2048;
            if (eA < n_edges) {
                int dv = dst[eA]; int sv = src[eA]; float rv = bond[eA];
                pack_edge(dv, sv, rv, sigma[sv], sigma[dv], hist, brA[j], recA[j]);
            } else brA[j] = 0xFFFFFFFFu;
            if (eB < n_edges) {
                int dv = dst[eB]; int sv = src[eB]; float rv = bond[eB];
                pack_edge(dv, sv, rv, sigma[sv], sigma[dv], hist, brB[j], recB[j]);
            } else brB[j] = 0xFFFFFFFFu;
        }
    }
    __syncthreads();

    // wave scan over NB buckets, 4 elems/lane (first wave, 256 >= NB+1)
    if (tid < 64) {
        const int base = tid * 4;
        uint32_t v[4]; uint32_t s = 0;
        #pragma unroll
        for (int j = 0; j < 4; ++j) { v[j] = (base + j < NB) ? hist[base + j] : 0u; s += v[j]; }
        uint32_t inc = s;
        #pragma unroll
        for (int d = 1; d < 64; d <<= 1) {
            uint32_t up = __shfl_up(inc, d, 64);
            if (tid >= d) inc += up;
        }
        uint32_t excl = inc - s;
        #pragma unroll
        for (int j = 0; j < 4; ++j) {
            if (base + j <= NB) scan_s[base + j] = excl;
            excl += v[j];
        }
    }
    __syncthreads();

    // register -> LDS scatter at scan[b] + rank
    #pragma unroll
    for (int j = 0; j < EPT; ++j)
        if (brA[j] != 0xFFFFFFFFu)
            buf[scan_s[brA[j] >> 16] + (brA[j] & 0xFFFFu)] = recA[j];
    #pragma unroll
    for (int j = 0; j < EPT; ++j)
        if (brB[j] != 0xFFFFFFFFu)
            buf[scan_s[brB[j] >> 16] + (brB[j] & 0xFFFFu)] = recB[j];
    __syncthreads();

    // offset table: the LDS scan, dumped as u16 (246 entries)
    if (tid <= NB)
        offs[(size_t)blockIdx.x * OFFS_STRIDE + tid] = (unsigned short)scan_s[tid];

    // dense block-major dump: fully coalesced vector stores, no checks
    {
        const vuint4* bs = (const vuint4*)buf;
        vuint4* os = (vuint4*)(rec_out + (size_t)blockIdx.x * EPB);
        #pragma unroll
        for (int i = 0; i < EPB / 4 / 256; ++i)      // 4 iterations
            __builtin_nontemporal_store(bs[tid + i * 256], os + tid + i * 256);
    }
}

// ---------------- pass 2: flat dense walk, record = local<<16 | fp16(v) ----------------
// Per-edge work is now {load u32 -> ds_add}. LDS ~11.5KB.
template<int WPB>
__global__ __launch_bounds__(256, 4) void p2_acc(
    const uint32_t*       __restrict__ rec_in,
    const unsigned short* __restrict__ offs,
    float*                __restrict__ partials,  // [NB*WPB][WINDOW]
    int n_nodes, int nblk)
{
    __shared__ float acc[WINDOW];                  // 8 KB
    __shared__ unsigned short offLo[SPAN_MAX];     // 1 KB
    __shared__ uint32_t cum[SPAN_MAX + 1];         // 2 KB — flat prefix of run lens

    const int g = blockIdx.x;
    const int b = g / WPB;
    const int w = g % WPB;

    vfloat4* accv = (vfloat4*)acc;
    for (int i = threadIdx.x; i < WINDOW / 4; i += 256)
        accv[i] = (vfloat4){0.f, 0.f, 0.f, 0.f};

    // my span of p1 blocks; stage offLo + run lengths (len into cum[] temp)
    const int span = (nblk + WPB - 1) / WPB;
    const int blk0 = w * span;
    int blkN = nblk - blk0;
    if (blkN > span) blkN = span;
    if (blkN < 0) blkN = 0;
    for (int i = threadIdx.x; i < blkN; i += 256) {
        size_t o = (size_t)(blk0 + i) * OFFS_STRIDE + b;
        unsigned short lo = offs[o];
        offLo[i] = lo;
        cum[i] = (uint32_t)offs[o + 1] - lo;     // run length (temp)
    }
    __syncthreads();

    // wave-0 exclusive scan of run lengths, 8 elems/lane (SPAN_MAX=512=64*8).
    if (threadIdx.x < 64) {
        const int base = threadIdx.x * 8;
        uint32_t v[8]; uint32_t s = 0;
        #pragma unroll
        for (int j = 0; j < 8; ++j) { v[j] = (base + j < blkN) ? cum[base + j] : 0u; s += v[j]; }
        uint32_t inc = s;
        #pragma unroll
        for (int d = 1; d < 64; d <<= 1) {
            uint32_t up = __shfl_up(inc, d, 64);
            if (threadIdx.x >= d) inc += up;
        }
        uint32_t excl = inc - s;
        #pragma unroll
        for (int j = 0; j < 8; ++j) { uint32_t t = v[j]; cum[base + j] = excl; excl += t; }
        if (threadIdx.x == 63) cum[SPAN_MAX] = inc;   // covers blkN == SPAN_MAX
    }
    __syncthreads();

    const int wave = threadIdx.x >> 6, lane = threadIdx.x & 63;
    const uint32_t T = cum[blkN];

    // contiguous flat slice per wave
    const uint32_t chunk = (T + 3) >> 2;
    const uint32_t f0    = (uint32_t)wave * chunk;
    uint32_t fend        = f0 + chunk;
    if (fend > T) fend = T;

    if (f0 < fend) {
        // seed run index: binary search for run containing f0 (wave-uniform)
        int l = 0, r = blkN;
        while (l < r) {
            int m = (l + r) >> 1;
            if (cum[m + 1] <= f0) l = m + 1; else r = m;
        }
        int i = l;

        for (uint32_t fb = f0; fb < fend; fb += 64) {
            uint32_t f = fb + lane;
            int ii = i;
            if (f < fend) {
                while (cum[ii + 1] <= f) ++ii;            // monotonic advance
                uint32_t k = f - cum[ii];
                size_t addr = (size_t)(blk0 + ii) * EPB + offLo[ii] + k;
                uint32_t rec = rec_in[addr];
                float v = __half2float(__ushort_as_half((unsigned short)rec));
                atomicAdd(&acc[rec >> 16], v);
            }
            i = __shfl(ii, 63);   // lane 63 holds the furthest run
        }
    }
    __syncthreads();

    // coalesced nt float4 flush
    vfloat4* outp = (vfloat4*)(partials + (size_t)g * WINDOW);
    for (int i = threadIdx.x; i < WINDOW / 4; i += 256)
        __builtin_nontemporal_store(accv[i], outp + i);
}

// ---------------- pass 3: reduce partials, apply charge ----------------
template<int WPB>
__global__ __launch_bounds__(256) void p3_reduce(
    const float* __restrict__ partials,
    const float* __restrict__ charge,
    float*       __restrict__ out, int n_nodes)
{
    int n = blockIdx.x * 256 + threadIdx.x;
    if (n >= n_nodes) return;
    unsigned b     = (unsigned)n >> WSHIFT;
    unsigned local = (unsigned)n & (WINDOW - 1);
    const float* p = partials + ((size_t)b * WPB) * WINDOW + local;
    float sum = 0.0f;
    #pragma unroll
    for (int w = 0; w < WPB; ++w)
        sum += __builtin_nontemporal_load(p + (size_t)w * WINDOW);
    out[n] = charge[n] * sum;
}

// ---------------- fallback: direct far-atomic ----------------
__global__ __launch_bounds__(256) void edge_msg_atomic(
    const float* __restrict__ charge, const float* __restrict__ sigma,
    const float* __restrict__ bond, const int* __restrict__ src,
    const int* __restrict__ dst, float* __restrict__ out, int n_edges)
{
    int i = blockIdx.x * blockDim.x + threadIdx.x;
    if (i < n_edges) {
        float ss = sigma[src[i]], sd = sigma[dst[i]];
        float msg = charge[dst[i]] * edge_val(bond[i], fmaf(ss, ss, sd * sd));
        atomicAdd(&out[dst[i]], msg);
    }
}

extern "C" void kernel_launch(void* const* d_in, const int* in_sizes, int n_in,
                              void* d_out, int out_size, void* d_ws, size_t ws_size,
                              hipStream_t stream) {
    const float* charge = (const float*)d_in[0];
    const float* sigma  = (const float*)d_in[1];
    const float* bond   = (const float*)d_in[2];
    const int*   src    = (const int*)d_in[3];
    const int*   dst    = (const int*)d_in[4];
    float* out = (float*)d_out;

    int n_nodes = in_sizes[0];
    int n_edges = in_sizes[2];

    int nblk = (n_edges + EPB - 1) / EPB;

    // ws: offs [nblk][256] u16 | rec [nblk][EPB] u32 | partials
    size_t offs_b = (size_t)nblk * OFFS_STRIDE * sizeof(unsigned short);
    size_t rec_b  = (size_t)nblk * EPB * sizeof(uint32_t);
    size_t base_b = offs_b + rec_b;

    // pick widest WPB whose partials fit the workspace & span fits LDS table
    int wpb = 0;
    {
        size_t p16 = (size_t)NB * 16 * WINDOW * sizeof(float);
        size_t p8  = (size_t)NB * 8  * WINDOW * sizeof(float);
        int span16 = (nblk + 15) / 16, span8 = (nblk + 7) / 8;
        if (base_b + p16 <= ws_size && span16 <= SPAN_MAX) wpb = 16;
        else if (base_b + p8 <= ws_size && span8 <= SPAN_MAX) wpb = 8;
    }

    if (n_nodes <= NB * WINDOW && wpb != 0) {
        unsigned short* offs = (unsigned short*)d_ws;
        uint32_t*       recp = (uint32_t*)((char*)d_ws + offs_b);
        float* partial = (float*)((char*)d_ws + base_b);

        p1_bin<<<nblk, 256, 0, stream>>>(bond, src, dst, sigma, offs, recp,
                                         n_edges);
        int blocks3 = (n_nodes + 255) / 256;
        if (wpb == 16) {
            p2_acc<16><<<NB * 16, 256, 0, stream>>>(recp, offs, partial,
                                                    n_nodes, nblk);
            p3_reduce<16><<<blocks3, 256, 0, stream>>>(partial, charge, out, n_nodes);
        } else {
            p2_acc<8><<<NB * 8, 256, 0, stream>>>(recp, offs, partial,
                                                  n_nodes, nblk);
            p3_reduce<8><<<blocks3, 256, 0, stream>>>(partial, charge, out, n_nodes);
        }
    } else {
        // fallback: direct atomics (correct, slower)
        (void)hipMemsetAsync(out, 0, (size_t)n_nodes * sizeof(float), stream);
        int blocks = (n_edges + 255) / 256;
        edge_msg_atomic<<<blocks, 256, 0, stream>>>(charge, sigma, bond, src, dst,
                                                    out, n_edges);
    }
}

// Round 9
// 337.479 us; speedup vs baseline: 1.1963x; 1.1963x over previous
//
#include <hip/hip_runtime.h>
#include <hip/hip_fp16.h>
#include <math.h>
#include <stdint.h>

// ---------------- problem constants ----------------
#define CUTOFF_F     5.0f
#define INV_CUTOFF   0.2f
#define KCOUL        14.3996454784936f
#define INV_SQRT2    0.7071067811865475f

// clang native vectors (HIP_vector_type is rejected by nontemporal builtins)
typedef int            vint4    __attribute__((ext_vector_type(4)));
typedef float          vfloat4  __attribute__((ext_vector_type(4)));
typedef uint32_t       vuint4   __attribute__((ext_vector_type(4)));
typedef unsigned short vushort8 __attribute__((ext_vector_type(8)));

// ---------------- plan ----------------
// ROUND-9: REMOVE p2'S SERIAL RUN-FIND + 4 RECORDS IN FLIGHT PER LANE.
// r8 (physics fused into p1) regressed the harness 327->403: p2's cost was
// never ALU, it's the 1-record-in-flight serial chain {cum-walk -> load ->
// gather -> atomic}. Revert to r7's proven p1/p3. New p2:
//  - after the cum scan, build runID[f] (u8, ~4.1K/WG) by PARALLEL binary
//    search + baseA[run] = blkbase+offLo-cum, so addr = baseA[runID[f]]+f
//    (one independent LDS read; no serial walk in the main loop);
//  - each lane processes f, f+256, f+512, f+768 per iteration: 4
//    independent {rec load -> sigma gather -> edge_val -> ds_add} chains.
// Concurrency: 24 waves/CU x 4 recs = ~96 in flight vs ~32 before.
#define WSHIFT        11
#define WINDOW        2048
#define NB            245                       // ceil(500000/2048)
#define EPT           8
#define EPB           4096                      // 2 batches * 256 thr * 8
#define OFFS_STRIDE   256                       // u16 slots per block (246 used)

// A&S 7.1.26 erf approx, x>=0, max abs err 1.5e-7
__device__ __forceinline__ float erf_approx(float x) {
    const float a1 = 0.254829592f, a2 = -0.284496736f, a3 = 1.421413741f,
                a4 = -1.453152027f, a5 = 1.061405429f, p = 0.3275911f;
    float t = __builtin_amdgcn_rcpf(fmaf(p, x, 1.0f));
    float poly = t * fmaf(t, fmaf(t, fmaf(t, fmaf(t, a5, a4), a3), a2), a1);
    return 1.0f - poly * __expf(-x * x);
}

// per-edge value WITHOUT the charge[dst] factor; s2sum = sig_s^2 + sig_d^2
__device__ __forceinline__ float edge_val(float rr, float s2sum) {
    float inv_gamma = rsqrtf(s2sum);
    float x  = rr * INV_CUTOFF;
    float fc = fmaf(x * x * x, fmaf(x, fmaf(-6.0f, x, 15.0f), -10.0f), 1.0f);
    fc = (rr <= CUTOFF_F) ? fc : 0.0f;
    return erf_approx(rr * INV_SQRT2 * inv_gamma) * fc * KCOUL
         * __builtin_amdgcn_rcpf(rr);
}

// ---------------- pass 1: block-major streaming counting-sort ----------------
// (round-7 version, verbatim: batch A {load->pack} then batch B {load->pack})
__global__ __launch_bounds__(256, 4) void p1_bin(
    const float* __restrict__ bond,
    const int*   __restrict__ src,
    const int*   __restrict__ dst,
    unsigned short* __restrict__ offs,    // [nblk][OFFS_STRIDE] u16 scan table
    uint32_t*       __restrict__ sl_out,  // [nblk][EPB] (src<<11 | local_dst)
    unsigned short* __restrict__ r_out,   // [nblk][EPB] fp16 bond length
    int n_edges)
{
    __shared__ uint32_t hist[NB];
    __shared__ uint32_t scan_s[NB + 1];
    __shared__ alignas(16) uint32_t       buf_sl[EPB];   // 16 KB
    __shared__ alignas(16) unsigned short buf_r[EPB];    //  8 KB

    const int tid = threadIdx.x;
    const int e0  = blockIdx.x * EPB;

    if (tid < NB) hist[tid] = 0;
    __syncthreads();

    uint32_t slA[EPT], brA[EPT], slB[EPT], brB[EPT];
    unsigned short hrA[EPT], hrB[EPT];

    const bool full = (e0 + EPB <= n_edges);
    if (full) {
        // ---- batch A: 6 vec4 loads, pack immediately, vec regs die ----
        {
            const vint4*   dp = (const vint4*)(dst + e0) + tid;
            const vint4*   sp = (const vint4*)(src + e0) + tid;
            const vfloat4* rp = (const vfloat4*)(bond + e0) + tid;
            vint4   d0 = __builtin_nontemporal_load(dp);
            vint4   d1 = __builtin_nontemporal_load(dp + 256);
            vint4   s0 = __builtin_nontemporal_load(sp);
            vint4   s1 = __builtin_nontemporal_load(sp + 256);
            vfloat4 r0 = __builtin_nontemporal_load(rp);
            vfloat4 r1 = __builtin_nontemporal_load(rp + 256);
            int   d[EPT] = {d0.x,d0.y,d0.z,d0.w,d1.x,d1.y,d1.z,d1.w};
            int   s[EPT] = {s0.x,s0.y,s0.z,s0.w,s1.x,s1.y,s1.z,s1.w};
            float r[EPT] = {r0.x,r0.y,r0.z,r0.w,r1.x,r1.y,r1.z,r1.w};
            #pragma unroll
            for (int j = 0; j < EPT; ++j) {
                unsigned b = (unsigned)d[j] >> WSHIFT;
                uint32_t rk = atomicAdd(&hist[b], 1u);
                brA[j] = (b << 16) | rk;
                slA[j] = ((uint32_t)s[j] << WSHIFT) | ((unsigned)d[j] & (WINDOW - 1));
                hrA[j] = __half_as_ushort(__float2half_rn(r[j]));
            }
        }
        // ---- batch B: same, offsets +512/+768 ----
        {
            const vint4*   dp = (const vint4*)(dst + e0) + tid;
            const vint4*   sp = (const vint4*)(src + e0) + tid;
            const vfloat4* rp = (const vfloat4*)(bond + e0) + tid;
            vint4   d2 = __builtin_nontemporal_load(dp + 512);
            vint4   d3 = __builtin_nontemporal_load(dp + 768);
            vint4   s2 = __builtin_nontemporal_load(sp + 512);
            vint4   s3 = __builtin_nontemporal_load(sp + 768);
            vfloat4 r2 = __builtin_nontemporal_load(rp + 512);
            vfloat4 r3 = __builtin_nontemporal_load(rp + 768);
            int   d[EPT] = {d2.x,d2.y,d2.z,d2.w,d3.x,d3.y,d3.z,d3.w};
            int   s[EPT] = {s2.x,s2.y,s2.z,s2.w,s3.x,s3.y,s3.z,s3.w};
            float r[EPT] = {r2.x,r2.y,r2.z,r2.w,r3.x,r3.y,r3.z,r3.w};
            #pragma unroll
            for (int j = 0; j < EPT; ++j) {
                unsigned b = (unsigned)d[j] >> WSHIFT;
                uint32_t rk = atomicAdd(&hist[b], 1u);
                brB[j] = (b << 16) | rk;
                slB[j] = ((uint32_t)s[j] << WSHIFT) | ((unsigned)d[j] & (WINDOW - 1));
                hrB[j] = __half_as_ushort(__float2half_rn(r[j]));
            }
        }
    } else {
        #pragma unroll
        for (int j = 0; j < EPT; ++j) {
            int eA = e0 + (j >> 2) * 1024 + tid * 4 + (j & 3);
            int eB = eA + 2048;
            if (eA < n_edges) {
                int dv = dst[eA]; int sv = src[eA]; float rv = bond[eA];
                unsigned b = (unsigned)dv >> WSHIFT;
                uint32_t rk = atomicAdd(&hist[b], 1u);
                brA[j] = (b << 16) | rk;
                slA[j] = ((uint32_t)sv << WSHIFT) | ((unsigned)dv & (WINDOW - 1));
                hrA[j] = __half_as_ushort(__float2half_rn(rv));
            } else brA[j] = 0xFFFFFFFFu;
            if (eB < n_edges) {
                int dv = dst[eB]; int sv = src[eB]; float rv = bond[eB];
                unsigned b = (unsigned)dv >> WSHIFT;
                uint32_t rk = atomicAdd(&hist[b], 1u);
                brB[j] = (b << 16) | rk;
                slB[j] = ((uint32_t)sv << WSHIFT) | ((unsigned)dv & (WINDOW - 1));
                hrB[j] = __half_as_ushort(__float2half_rn(rv));
            } else brB[j] = 0xFFFFFFFFu;
        }
    }
    __syncthreads();

    // wave scan over NB buckets, 4 elems/lane (first wave, 256 >= NB+1)
    if (tid < 64) {
        const int base = tid * 4;
        uint32_t v[4]; uint32_t s = 0;
        #pragma unroll
        for (int j = 0; j < 4; ++j) { v[j] = (base + j < NB) ? hist[base + j] : 0u; s += v[j]; }
        uint32_t inc = s;
        #pragma unroll
        for (int d = 1; d < 64; d <<= 1) {
            uint32_t up = __shfl_up(inc, d, 64);
            if (tid >= d) inc += up;
        }
        uint32_t excl = inc - s;
        #pragma unroll
        for (int j = 0; j < 4; ++j) {
            if (base + j <= NB) scan_s[base + j] = excl;
            excl += v[j];
        }
    }
    __syncthreads();

    // register -> LDS scatter at scan[b] + rank
    #pragma unroll
    for (int j = 0; j < EPT; ++j)
        if (brA[j] != 0xFFFFFFFFu) {
            uint32_t p = scan_s[brA[j] >> 16] + (brA[j] & 0xFFFFu);
            buf_sl[p] = slA[j]; buf_r[p] = hrA[j];
        }
    #pragma unroll
    for (int j = 0; j < EPT; ++j)
        if (brB[j] != 0xFFFFFFFFu) {
            uint32_t p = scan_s[brB[j] >> 16] + (brB[j] & 0xFFFFu);
            buf_sl[p] = slB[j]; buf_r[p] = hrB[j];
        }
    __syncthreads();

    // offset table: the LDS scan, dumped as u16 (246 entries)
    if (tid <= NB)
        offs[(size_t)blockIdx.x * OFFS_STRIDE + tid] = (unsigned short)scan_s[tid];

    // dense block-major dump: fully coalesced vector stores, no checks
    {
        const vuint4* bs = (const vuint4*)buf_sl;
        vuint4* os = (vuint4*)(sl_out + (size_t)blockIdx.x * EPB);
        #pragma unroll
        for (int i = 0; i < EPB / 4 / 256; ++i)      // 4 iterations
            __builtin_nontemporal_store(bs[tid + i * 256], os + tid + i * 256);
        const vushort8* br = (const vushort8*)buf_r;
        vushort8* orr = (vushort8*)(r_out + (size_t)blockIdx.x * EPB);
        #pragma unroll
        for (int i = 0; i < EPB / 8 / 256; ++i)      // 2 iterations
            __builtin_nontemporal_store(br[tid + i * 256], orr + tid + i * 256);
    }
}

// ---------------- pass 2: runID-table walk, 4 records in flight per lane ----------------
// RID: u8 when span<=255 (WPB=16), u16 otherwise. T_MAX >> +16sigma of E[T].
template<int WPB, typename RID, int T_MAX, int SPAN_CAP>
__global__ __launch_bounds__(256, 4) void p2_acc(
    const uint32_t*       __restrict__ sl_in,
    const unsigned short* __restrict__ r_in,
    const unsigned short* __restrict__ offs,
    const float*          __restrict__ sigma,
    float*                __restrict__ partials,  // [NB*WPB][WINDOW]
    int n_nodes, int nblk)
{
    __shared__ float acc[WINDOW];                  // 8 KB
    __shared__ float sig[WINDOW];                  // 8 KB — dst-side sigma
    __shared__ uint32_t cum[SPAN_CAP + 1];         // prefix of run lengths
    __shared__ uint32_t baseA[SPAN_CAP];           // blkbase + offLo - cum
    __shared__ RID      runID[T_MAX];              // flat index -> run

    const int g = blockIdx.x;
    const int b = g / WPB;
    const int w = g % WPB;

    vfloat4* accv = (vfloat4*)acc;
    for (int i = threadIdx.x; i < WINDOW / 4; i += 256)
        accv[i] = (vfloat4){0.f, 0.f, 0.f, 0.f};

    const int nbase  = b << WSHIFT;
    const int nvalid = (n_nodes - nbase < WINDOW) ? (n_nodes - nbase) : WINDOW;
    if (nvalid == WINDOW) {
        vfloat4* sv = (vfloat4*)sig;
        const vfloat4* gp = (const vfloat4*)(sigma + nbase);
        for (int i = threadIdx.x; i < WINDOW / 4; i += 256) sv[i] = gp[i];
    } else {
        for (int i = threadIdx.x; i < WINDOW; i += 256)
            sig[i] = (i < nvalid) ? sigma[nbase + i] : 0.f;
    }

    // stage run lengths (into cum temp) + provisional baseA
    const int span = (nblk + WPB - 1) / WPB;
    const int blk0 = w * span;
    int blkN = nblk - blk0;
    if (blkN > span) blkN = span;
    if (blkN < 0) blkN = 0;
    for (int i = threadIdx.x; i < blkN; i += 256) {
        size_t o = (size_t)(blk0 + i) * OFFS_STRIDE + b;
        uint32_t lo = offs[o];
        cum[i]   = (uint32_t)offs[o + 1] - lo;            // run length (temp)
        baseA[i] = (uint32_t)(blk0 + i) * EPB + lo;       // - cum[i] later
    }
    __syncthreads();

    // wave-0 exclusive scan (SPAN_CAP/64 elems per lane)
    if (threadIdx.x < 64) {
        constexpr int EL = SPAN_CAP / 64;
        const int base = threadIdx.x * EL;
        uint32_t v[EL]; uint32_t s = 0;
        #pragma unroll
        for (int j = 0; j < EL; ++j) { v[j] = (base + j < blkN) ? cum[base + j] : 0u; s += v[j]; }
        uint32_t inc = s;
        #pragma unroll
        for (int d = 1; d < 64; d <<= 1) {
            uint32_t up = __shfl_up(inc, d, 64);
            if (threadIdx.x >= d) inc += up;
        }
        uint32_t excl = inc - s;
        #pragma unroll
        for (int j = 0; j < EL; ++j) { uint32_t t = v[j]; cum[base + j] = excl; excl += t; }
        if (threadIdx.x == 63) cum[SPAN_CAP] = inc;   // covers blkN == SPAN_CAP
    }
    __syncthreads();

    const uint32_t T  = cum[blkN];
    const uint32_t Tc = (T < (uint32_t)T_MAX) ? T : (uint32_t)T_MAX;

    // finalize baseA and build runID[] by parallel binary search
    for (int i = threadIdx.x; i < blkN; i += 256) baseA[i] -= cum[i];
    for (uint32_t p = threadIdx.x; p < Tc; p += 256) {
        int l = 0, r = blkN;
        while (l < r) {
            int m = (l + r) >> 1;
            if (cum[m + 1] <= p) l = m + 1; else r = m;
        }
        runID[p] = (RID)l;
    }
    __syncthreads();

    // main loop: 4 independent records per lane per iteration
    for (uint32_t f0 = threadIdx.x; f0 < Tc; f0 += 1024u) {
        uint32_t sl4[4]; unsigned short rh4[4]; bool ok[4];
        #pragma unroll
        for (int j = 0; j < 4; ++j) {
            uint32_t f = f0 + (uint32_t)j * 256u;
            ok[j] = (f < Tc);
            if (ok[j]) {
                uint32_t a = baseA[runID[f]] + f;
                sl4[j] = sl_in[a];
                rh4[j] = r_in[a];
            }
        }
        float ss4[4], sd4[4];
        #pragma unroll
        for (int j = 0; j < 4; ++j)
            if (ok[j]) {
                ss4[j] = sigma[sl4[j] >> WSHIFT];
                sd4[j] = sig[sl4[j] & (WINDOW - 1)];
            }
        #pragma unroll
        for (int j = 0; j < 4; ++j)
            if (ok[j]) {
                float rr = __half2float(__ushort_as_half(rh4[j]));
                float v  = edge_val(rr, fmaf(ss4[j], ss4[j], sd4[j] * sd4[j]));
                atomicAdd(&acc[sl4[j] & (WINDOW - 1)], v);
            }
    }

    // overflow tail (T > T_MAX: ~never; per-record binary search)
    for (uint32_t f = (uint32_t)T_MAX + threadIdx.x; f < T; f += 256u) {
        int l = 0, r = blkN;
        while (l < r) {
            int m = (l + r) >> 1;
            if (cum[m + 1] <= f) l = m + 1; else r = m;
        }
        uint32_t a = baseA[l] + f;
        uint32_t sl = sl_in[a];
        float rr = __half2float(__ushort_as_half(r_in[a]));
        float ss = sigma[sl >> WSHIFT];
        float sd = sig[sl & (WINDOW - 1)];
        float v  = edge_val(rr, fmaf(ss, ss, sd * sd));
        atomicAdd(&acc[sl & (WINDOW - 1)], v);
    }
    __syncthreads();

    // coalesced nt float4 flush
    vfloat4* outp = (vfloat4*)(partials + (size_t)g * WINDOW);
    for (int i = threadIdx.x; i < WINDOW / 4; i += 256)
        __builtin_nontemporal_store(accv[i], outp + i);
}

// ---------------- pass 3: reduce partials, apply charge ----------------
template<int WPB>
__global__ __launch_bounds__(256) void p3_reduce(
    const float* __restrict__ partials,
    const float* __restrict__ charge,
    float*       __restrict__ out, int n_nodes)
{
    int n = blockIdx.x * 256 + threadIdx.x;
    if (n >= n_nodes) return;
    unsigned b     = (unsigned)n >> WSHIFT;
    unsigned local = (unsigned)n & (WINDOW - 1);
    const float* p = partials + ((size_t)b * WPB) * WINDOW + local;
    float sum = 0.0f;
    #pragma unroll
    for (int w = 0; w < WPB; ++w)
        sum += __builtin_nontemporal_load(p + (size_t)w * WINDOW);
    out[n] = charge[n] * sum;
}

// ---------------- fallback: direct far-atomic ----------------
__global__ __launch_bounds__(256) void edge_msg_atomic(
    const float* __restrict__ charge, const float* __restrict__ sigma,
    const float* __restrict__ bond, const int* __restrict__ src,
    const int* __restrict__ dst, float* __restrict__ out, int n_edges)
{
    int i = blockIdx.x * blockDim.x + threadIdx.x;
    if (i < n_edges) {
        float ss = sigma[src[i]], sd = sigma[dst[i]];
        float msg = charge[dst[i]] * edge_val(bond[i], fmaf(ss, ss, sd * sd));
        atomicAdd(&out[dst[i]], msg);
    }
}

extern "C" void kernel_launch(void* const* d_in, const int* in_sizes, int n_in,
                              void* d_out, int out_size, void* d_ws, size_t ws_size,
                              hipStream_t stream) {
    const float* charge = (const float*)d_in[0];
    const float* sigma  = (const float*)d_in[1];
    const float* bond   = (const float*)d_in[2];
    const int*   src    = (const int*)d_in[3];
    const int*   dst    = (const int*)d_in[4];
    float* out = (float*)d_out;

    int n_nodes = in_sizes[0];
    int n_edges = in_sizes[2];

    int nblk = (n_edges + EPB - 1) / EPB;

    // ws: offs [nblk][256] u16 | sl [nblk][EPB] u32 | r [nblk][EPB] u16 | partials
    size_t offs_b = (size_t)nblk * OFFS_STRIDE * sizeof(unsigned short);
    size_t sl_b   = (size_t)nblk * EPB * sizeof(uint32_t);
    size_t r_b    = (size_t)nblk * EPB * sizeof(unsigned short);
    size_t base_b = offs_b + sl_b + r_b;

    // pick widest WPB whose partials fit the workspace & span fits tables
    int wpb = 0;
    {
        size_t p16 = (size_t)NB * 16 * WINDOW * sizeof(float);
        size_t p8  = (size_t)NB * 8  * WINDOW * sizeof(float);
        int span16 = (nblk + 15) / 16, span8 = (nblk + 7) / 8;
        if (base_b + p16 <= ws_size && span16 <= 256) wpb = 16;
        else if (base_b + p8 <= ws_size && span8 <= 512) wpb = 8;
    }

    if (n_nodes <= NB * WINDOW && wpb != 0) {
        unsigned short* offs = (unsigned short*)d_ws;
        uint32_t*       slp  = (uint32_t*)((char*)d_ws + offs_b);
        unsigned short* rp   = (unsigned short*)((char*)d_ws + offs_b + sl_b);
        float* partial = (float*)((char*)d_ws + base_b);

        p1_bin<<<nblk, 256, 0, stream>>>(bond, src, dst, offs, slp, rp, n_edges);
        int blocks3 = (n_nodes + 255) / 256;
        if (wpb == 16) {
            p2_acc<16, unsigned char, 6144, 256>
                <<<NB * 16, 256, 0, stream>>>(slp, rp, offs, sigma, partial,
                                              n_nodes, nblk);
            p3_reduce<16><<<blocks3, 256, 0, stream>>>(partial, charge, out, n_nodes);
        } else {
            p2_acc<8, unsigned short, 10240, 512>
                <<<NB * 8, 256, 0, stream>>>(slp, rp, offs, sigma, partial,
                                             n_nodes, nblk);
            p3_reduce<8><<<blocks3, 256, 0, stream>>>(partial, charge, out, n_nodes);
        }
    } else {
        // fallback: direct atomics (correct, slower)
        (void)hipMemsetAsync(out, 0, (size_t)n_nodes * sizeof(float), stream);
        int blocks = (n_edges + 255) / 256;
        edge_msg_atomic<<<blocks, 256, 0, stream>>>(charge, sigma, bond, src, dst,
                                                    out, n_edges);
    }
}